// Round 14
// baseline (94.262 us; speedup 1.0000x reference)
//
#include <hip/hip_runtime.h>
#include <hip/hip_fp16.h>

// W8X8Linear: per-row int8 quant (x and w), int8 GEMM via MFMA, dequant+bias.
// M=B*S=32768, N=1024, K=1024 (derived from in_sizes at launch).
//
// Exact-replication notes:
//  - jnp.round == round-half-even == rintf (v_rndne_f32)
//  - scale 127.0f/max (fp32 div) then fp32 mul, like the reference
//  - int32 accumulation == reference's fp32 einsum (|acc| < 2^24, exact)
//  - dequant: * (1/16129), fp16 RN cast, fp32 * (xmax*wmax) + bias
//
// R6: K-BLOCKED quant layout q[kb][row][64] (contiguous staging): 95us.
// R9: thin regs (3 blocks/CU), BK=64, both operands LDS-staged, rotated
//     counted vmcnt: 89us — BEST. R10/R11/R12: A-direct variants: 111/100/94
//     (per-wave VMEM loads of A cost more than global_load_lds staging).
// R13: R9 + ONE change: 3 LDS buffers, depth-2 prefetch. Tile kt's loads are
//     issued at iter kt-2 -> TWO iterations (~800-1000cy) of latency cover
//     (vs depth-1's ~400cy < L2/L3 latency). vmcnt(8) in steady state: 8
//     loads stay in flight across the barrier; tail 4 -> 0. Occupancy
//     unchanged (48KB LDS still 3 blocks/CU = reg-bound) -> isolates depth.

typedef int i32x4 __attribute__((ext_vector_type(4)));

#define BM 128
#define BN 128
#define KB 64  // K-bytes per tile = quant layout block size

// -------- quantize: one block per row; OUTPUT IS K-BLOCKED q[kb][row][64] ---
__global__ __launch_bounds__(256) void quant_rows_kernel(
    const float* __restrict__ in, signed char* __restrict__ q,
    float* __restrict__ rowmax, int K, int R) {
  const int row = blockIdx.x;
  const int t = threadIdx.x;
  const size_t base = (size_t)row * K;
  float4 v = reinterpret_cast<const float4*>(in + base)[t];
  float a = fmaxf(fmaxf(fabsf(v.x), fabsf(v.y)), fmaxf(fabsf(v.z), fabsf(v.w)));
#pragma unroll
  for (int off = 32; off > 0; off >>= 1) a = fmaxf(a, __shfl_xor(a, off, 64));
  __shared__ float smax[4];
  if ((t & 63) == 0) smax[t >> 6] = a;
  __syncthreads();
  float m = fmaxf(fmaxf(smax[0], smax[1]), fmaxf(smax[2], smax[3]));
  float s = 127.0f / m;  // fp32 divide, same as reference
  char4 qq;
  qq.x = (signed char)(int)rintf(v.x * s);
  qq.y = (signed char)(int)rintf(v.y * s);
  qq.z = (signed char)(int)rintf(v.z * s);
  qq.w = (signed char)(int)rintf(v.w * s);
  // elems k = 4t..4t+3 -> kb = t>>4, within-block byte (t&15)*4
  const int kb = t >> 4;
  signed char* dst = q + (size_t)kb * R * KB + (size_t)row * KB + (t & 15) * 4;
  *reinterpret_cast<char4*>(dst) = qq;
  if (t == 0) rowmax[row] = m;
}

// ---------------- int8 GEMM, 128x128 tile, 4 waves (2x2), BK=64 -------------
__device__ __forceinline__ void gload_lds16(const void* g, void* l) {
  __builtin_amdgcn_global_load_lds(
      (const __attribute__((address_space(1))) unsigned char*)g,
      (__attribute__((address_space(3))) unsigned char*)l, 16, 0, 0);
}

__global__ __launch_bounds__(256, 4) void w8x8_gemm_kernel(
    const signed char* __restrict__ Aq, const signed char* __restrict__ Bq,
    const float* __restrict__ Amax, const float* __restrict__ Bmax,
    const float* __restrict__ bias, float* __restrict__ out,
    int M, int N, int K, int cpx) {
  // 3 buffers x (A 8 KB + B 8 KB) = 48 KB -> 3 blocks/CU (same as reg bound).
  __shared__ __align__(16) signed char ldsA[3][BM * KB];
  __shared__ __align__(16) signed char ldsB[3][BN * KB];
  const int t = threadIdx.x;
  const int lane = t & 63;
  const int wave = t >> 6;
  const int wrow = wave >> 1, wcol = wave & 1;

  // XCD-chunked swizzle: contiguous bm-run per XCD (A slice 4 MB = one L2).
  const int nbn = N / BN;
  const int bid = blockIdx.x;
  const int tile = (bid & 7) * cpx + (bid >> 3);
  const int bm = tile / nbn, bn = tile % nbn;

  // K-blocked layout: operand tile kt is CONTIGUOUS 8 KB at
  // q + kt*R*64 + tilerow0*64.
  const size_t kbA = (size_t)M * KB;
  const size_t kbB = (size_t)N * KB;
  const signed char* Abase = Aq + (size_t)bm * BM * KB;
  const signed char* Bbase = Bq + (size_t)bn * BN * KB;

  // Staging: 8 KB/operand = 512 16B-chunks = 2 stmts x 256 thr. LDS dest
  // linear (chunk c -> byte c*16). Source pre-swizzled: physical chunk p of
  // row r holds logical chunk p ^ ((r>>1)&3). One offset serves both stmts.
  const int rS = t >> 2;
  const int gs0 = (rS << 6) | ((((t & 3) ^ ((rS >> 1) & 3))) << 4);
  const int dst0 = t * 16;

  // Fragment reads (swizzled): frag row ra, k-chunk fq -> physical chunk
  // fq ^ ((ra>>1)&3); (ra>>1)&3 == (fr>>1)&3 (row bases multiples of 16).
  const int fr = lane & 15, fq = lane >> 4;
  const int pcs = (fq ^ ((fr >> 1) & 3)) << 4;
  int aoff[4], boff[4];
#pragma unroll
  for (int m = 0; m < 4; ++m) {
    aoff[m] = (wrow * 64 + m * 16 + fr) * KB + pcs;
    boff[m] = (wcol * 64 + m * 16 + fr) * KB + pcs;
  }

  i32x4 acc[4][4];
#pragma unroll
  for (int m = 0; m < 4; ++m)
#pragma unroll
    for (int n = 0; n < 4; ++n) acc[m][n] = (i32x4){0, 0, 0, 0};

#define STAGE(bf, kt)                                                  \
  do {                                                                 \
    const signed char* ga = Abase + (size_t)(kt) * kbA + gs0;          \
    const signed char* gb = Bbase + (size_t)(kt) * kbB + gs0;          \
    gload_lds16(ga, &ldsA[bf][dst0]);                                  \
    gload_lds16(ga + 4096, &ldsA[bf][dst0 + 4096]);                    \
    gload_lds16(gb, &ldsB[bf][dst0]);                                  \
    gload_lds16(gb + 4096, &ldsB[bf][dst0 + 4096]);                    \
  } while (0)

  const int NT = K / KB;  // 16
  // Prologue: stage tiles 0 and 1 (depth-2 head).
  STAGE(0, 0);
  STAGE(1, 1);

  int cb = 0;  // buffer holding tile kt
  for (int kt = 0; kt < NT; ++kt) {
    const bool p2 = (kt + 2 < NT), p1 = (kt + 1 < NT);
    // 1) stage tile kt+2 into the buffer freed at end of iter kt-1
    if (p2) {
      int sb = cb + 2;
      if (sb >= 3) sb -= 3;
      STAGE(sb, kt + 2);
    }
    // 2) counted wait: tile kt's 4 loads were issued at iter kt-2 -> TWO
    //    iterations of compute as cover. kt+1's and kt+2's 8 loads stay in
    //    flight ACROSS the barrier (in-order retirement, m135).
    if (p2)
      asm volatile("s_waitcnt vmcnt(8)" ::: "memory");
    else if (p1)
      asm volatile("s_waitcnt vmcnt(4)" ::: "memory");
    else
      asm volatile("s_waitcnt vmcnt(0)" ::: "memory");
    __builtin_amdgcn_s_barrier();  // all waves' tile-kt loads landed

    // 3) compute tile kt
    const signed char* lA = ldsA[cb];
    const signed char* lB = ldsB[cb];
    i32x4 a[4], b[4];
#pragma unroll
    for (int m = 0; m < 4; ++m) {
      a[m] = *reinterpret_cast<const i32x4*>(lA + aoff[m]);
      b[m] = *reinterpret_cast<const i32x4*>(lB + boff[m]);
    }
    __builtin_amdgcn_s_setprio(1);
#pragma unroll
    for (int m = 0; m < 4; ++m)
#pragma unroll
      for (int n = 0; n < 4; ++n)
        acc[m][n] = __builtin_amdgcn_mfma_i32_16x16x64_i8(a[m], b[n],
                                                          acc[m][n], 0, 0, 0);
    __builtin_amdgcn_s_setprio(0);

    // 4) end-of-iter barrier: all waves done reading buf cb, so iter kt+1
    //    may stage into it (it becomes sb at kt+1). No vmcnt here.
    if (p1) __builtin_amdgcn_s_barrier();
    cb = (cb + 1 == 3) ? 0 : cb + 1;
  }
#undef STAGE

  // Epilogue: C/D layout col = lane&15, row = (lane>>4)*4 + reg.
  // Per store instr: 4 segments x 64 B (good coalescing).
  const int row0 = bm * BM + wrow * 64;
  const int col0 = bn * BN + wcol * 64;
  const float C = 1.0f / 16129.0f;
  float wmx[4], bs[4];
#pragma unroll
  for (int n = 0; n < 4; ++n) {
    int col = col0 + n * 16 + fr;
    wmx[n] = Bmax[col];
    bs[n] = bias[col];
  }
#pragma unroll
  for (int m = 0; m < 4; ++m) {
#pragma unroll
    for (int r = 0; r < 4; ++r) {
      int row = row0 + m * 16 + fq * 4 + r;
      float xm = Amax[row];
      float* orow = out + (size_t)row * N;
#pragma unroll
      for (int n = 0; n < 4; ++n) {
        float v = (float)acc[m][n][r] * C;
        float h = __half2float(__float2half_rn(v));  // fp16 rounding step
        orow[col0 + n * 16 + fr] = h * (xm * wmx[n]) + bs[n];
      }
    }
  }
}

extern "C" void kernel_launch(void* const* d_in, const int* in_sizes, int n_in,
                              void* d_out, int out_size, void* d_ws, size_t ws_size,
                              hipStream_t stream) {
  const float* x = (const float*)d_in[0];     // [B,S,K] fp32
  const float* w = (const float*)d_in[1];     // [N,K] fp32
  const float* bias = (const float*)d_in[2];  // [N] fp32
  float* out = (float*)d_out;                 // [B,S,N] fp32

  const int N = in_sizes[2];
  const int K = in_sizes[1] / N;   // 1024
  const int M = in_sizes[0] / K;   // 32768

  // workspace layout: x_q | w_q | x_max | w_max  (~34.7 MB total)
  signed char* xq = (signed char*)d_ws;
  signed char* wq = xq + (size_t)M * K;
  float* xmax = (float*)(wq + (size_t)N * K);
  float* wmax = xmax + M;

  quant_rows_kernel<<<M, 256, 0, stream>>>(x, xq, xmax, K, M);
  quant_rows_kernel<<<N, 256, 0, stream>>>(w, wq, wmax, K, N);

  const int nwg = (M / BM) * (N / BN);  // 2048, divisible by 8
  const int cpx = nwg / 8;
  w8x8_gemm_kernel<<<nwg, 256, 0, stream>>>(xq, wq, xmax, wmax, bias, out,
                                            M, N, K, cpx);
}

// Round 16
// 86.700 us; speedup vs baseline: 1.0872x; 1.0872x over previous
//
#include <hip/hip_runtime.h>
#include <hip/hip_fp16.h>

// W8X8Linear: per-row int8 quant (x and w), int8 GEMM via MFMA, dequant+bias.
// M=B*S=32768, N=1024, K=1024 (derived from in_sizes at launch).
//
// Exact-replication notes:
//  - jnp.round == round-half-even == rintf (v_rndne_f32)
//  - scale 127.0f/max (fp32 div) then fp32 mul, like the reference
//  - int32 accumulation == reference's fp32 einsum (|acc| < 2^24, exact)
//  - dequant: * (1/16129), fp16 RN cast, fp32 * (xmax*wmax) + bias
//
// Ladder: R6 K-BLOCKED quant layout q[kb][row][64] (1-KB-contiguous staging
//   statements): 95us. R9 thin regs -> 4 waves/SIMD, BK=64, 2-buf rotated
//   counted vmcnt: 89us BEST. Nulls: counted-vmcnt/depth-2 x3, fine-phase x2,
//   A-direct x4, forced min-waves (spill), single-barrier 2-buf (RACE —
//   R14 failed correctness: STAGE at iter kt precedes barrier_kt, lagging
//   wave still reads buf[(kt-1)&1] == staging target. End barrier is
//   load-bearing with 2 buffers).
// R15: R9 restored byte-for-byte + merged quant launch (single grid M+N,
//   per-block pointer select) to remove one launch boundary.

typedef int i32x4 __attribute__((ext_vector_type(4)));

#define BM 128
#define BN 128
#define KB 64  // K-bytes per tile = quant layout block size

// ---- quantize: one block per row of x (b<M) or w (b>=M); K-BLOCKED output --
__global__ __launch_bounds__(256) void quant_rows_kernel(
    const float* __restrict__ x, signed char* __restrict__ xq,
    float* __restrict__ xmax, const float* __restrict__ w,
    signed char* __restrict__ wq, float* __restrict__ wmax, int K, int M,
    int N) {
  const int b = blockIdx.x;
  const bool isx = (b < M);
  const int row = isx ? b : b - M;
  const int R = isx ? M : N;
  const float* in = isx ? x : w;
  signed char* q = isx ? xq : wq;
  float* rowmax = isx ? xmax : wmax;

  const int t = threadIdx.x;
  const size_t base = (size_t)row * K;
  float4 v = reinterpret_cast<const float4*>(in + base)[t];
  float a = fmaxf(fmaxf(fabsf(v.x), fabsf(v.y)), fmaxf(fabsf(v.z), fabsf(v.w)));
#pragma unroll
  for (int off = 32; off > 0; off >>= 1) a = fmaxf(a, __shfl_xor(a, off, 64));
  __shared__ float smax[4];
  if ((t & 63) == 0) smax[t >> 6] = a;
  __syncthreads();
  float m = fmaxf(fmaxf(smax[0], smax[1]), fmaxf(smax[2], smax[3]));
  float s = 127.0f / m;  // fp32 divide, same as reference
  char4 qq;
  qq.x = (signed char)(int)rintf(v.x * s);
  qq.y = (signed char)(int)rintf(v.y * s);
  qq.z = (signed char)(int)rintf(v.z * s);
  qq.w = (signed char)(int)rintf(v.w * s);
  // elems k = 4t..4t+3 -> kb = t>>4, within-block byte (t&15)*4
  const int kb = t >> 4;
  signed char* dst = q + (size_t)kb * R * KB + (size_t)row * KB + (t & 15) * 4;
  *reinterpret_cast<char4*>(dst) = qq;
  if (t == 0) rowmax[row] = m;
}

// ---------------- int8 GEMM, 128x128 tile, 4 waves (2x2), BK=64 -------------
__device__ __forceinline__ void gload_lds16(const void* g, void* l) {
  __builtin_amdgcn_global_load_lds(
      (const __attribute__((address_space(1))) unsigned char*)g,
      (__attribute__((address_space(3))) unsigned char*)l, 16, 0, 0);
}

__global__ __launch_bounds__(256, 4) void w8x8_gemm_kernel(
    const signed char* __restrict__ Aq, const signed char* __restrict__ Bq,
    const float* __restrict__ Amax, const float* __restrict__ Bmax,
    const float* __restrict__ bias, float* __restrict__ out,
    int M, int N, int K, int cpx) {
  // 2 buffers x (A 8 KB + B 8 KB) = 32 KB -> 4 blocks/CU (VGPR-bound).
  __shared__ __align__(16) signed char ldsA[2][BM * KB];
  __shared__ __align__(16) signed char ldsB[2][BN * KB];
  const int t = threadIdx.x;
  const int lane = t & 63;
  const int wave = t >> 6;
  const int wrow = wave >> 1, wcol = wave & 1;

  // XCD-chunked swizzle: contiguous bm-run per XCD (A slice 4 MB = one L2).
  const int nbn = N / BN;
  const int bid = blockIdx.x;
  const int tile = (bid & 7) * cpx + (bid >> 3);
  const int bm = tile / nbn, bn = tile % nbn;

  // K-blocked layout: operand tile kt is CONTIGUOUS 8 KB at
  // q + kt*R*64 + tilerow0*64.
  const size_t kbA = (size_t)M * KB;
  const size_t kbB = (size_t)N * KB;
  const signed char* Abase = Aq + (size_t)bm * BM * KB;
  const signed char* Bbase = Bq + (size_t)bn * BN * KB;

  // Staging: 8 KB/operand = 512 16B-chunks = 2 stmts x 256 thr. LDS dest
  // linear (chunk c -> byte c*16). Source pre-swizzled: physical chunk p of
  // row r holds logical chunk p ^ ((r>>1)&3). One offset serves both stmts.
  const int rS = t >> 2;
  const int gs0 = (rS << 6) | ((((t & 3) ^ ((rS >> 1) & 3))) << 4);
  const int dst0 = t * 16;

  // Fragment reads (swizzled): frag row ra, k-chunk fq -> physical chunk
  // fq ^ ((ra>>1)&3); (ra>>1)&3 == (fr>>1)&3 (row bases multiples of 16).
  const int fr = lane & 15, fq = lane >> 4;
  const int pcs = (fq ^ ((fr >> 1) & 3)) << 4;
  int aoff[4], boff[4];
#pragma unroll
  for (int m = 0; m < 4; ++m) {
    aoff[m] = (wrow * 64 + m * 16 + fr) * KB + pcs;
    boff[m] = (wcol * 64 + m * 16 + fr) * KB + pcs;
  }

  i32x4 acc[4][4];
#pragma unroll
  for (int m = 0; m < 4; ++m)
#pragma unroll
    for (int n = 0; n < 4; ++n) acc[m][n] = (i32x4){0, 0, 0, 0};

#define STAGE(bf, kt)                                                  \
  do {                                                                 \
    const signed char* ga = Abase + (size_t)(kt) * kbA + gs0;          \
    const signed char* gb = Bbase + (size_t)(kt) * kbB + gs0;          \
    gload_lds16(ga, &ldsA[bf][dst0]);                                  \
    gload_lds16(ga + 4096, &ldsA[bf][dst0 + 4096]);                    \
    gload_lds16(gb, &ldsB[bf][dst0]);                                  \
    gload_lds16(gb + 4096, &ldsB[bf][dst0 + 4096]);                    \
  } while (0)

  const int NT = K / KB;  // 16
  STAGE(0, 0);

  for (int kt = 0; kt < NT; ++kt) {
    const bool pf = (kt + 1 < NT);
    // 1) issue next tile's staging (other buffer; its readers all passed the
    //    END barrier of iter kt-1 — that barrier is load-bearing, see R14).
    if (pf) STAGE((kt + 1) & 1, kt + 1);
    // 2) counted wait: tile kt's 4 loads (issued LAST iter, a full iteration
    //    of cover) retired; kt+1's 4 stay in flight ACROSS the barrier.
    if (pf)
      asm volatile("s_waitcnt vmcnt(4)" ::: "memory");
    else
      asm volatile("s_waitcnt vmcnt(0)" ::: "memory");
    __builtin_amdgcn_s_barrier();  // all waves' tile-kt loads landed

    // 3) compute tile kt
    const signed char* lA = ldsA[kt & 1];
    const signed char* lB = ldsB[kt & 1];
    i32x4 a[4], b[4];
#pragma unroll
    for (int m = 0; m < 4; ++m) {
      a[m] = *reinterpret_cast<const i32x4*>(lA + aoff[m]);
      b[m] = *reinterpret_cast<const i32x4*>(lB + boff[m]);
    }
    __builtin_amdgcn_s_setprio(1);
#pragma unroll
    for (int m = 0; m < 4; ++m)
#pragma unroll
      for (int n = 0; n < 4; ++n)
        acc[m][n] = __builtin_amdgcn_mfma_i32_16x16x64_i8(a[m], b[n],
                                                          acc[m][n], 0, 0, 0);
    __builtin_amdgcn_s_setprio(0);

    // 4) END barrier: protects buf (kt+1)&1 from iter kt+1's staging while
    //    lagging waves still read it. REQUIRED with 2 buffers (R14 raced).
    if (pf) __builtin_amdgcn_s_barrier();
  }
#undef STAGE

  // Epilogue: C/D layout col = lane&15, row = (lane>>4)*4 + reg.
  // Per store instr: 4 segments x 64 B (good coalescing).
  const int row0 = bm * BM + wrow * 64;
  const int col0 = bn * BN + wcol * 64;
  const float C = 1.0f / 16129.0f;
  float wmx[4], bs[4];
#pragma unroll
  for (int n = 0; n < 4; ++n) {
    int col = col0 + n * 16 + fr;
    wmx[n] = Bmax[col];
    bs[n] = bias[col];
  }
#pragma unroll
  for (int m = 0; m < 4; ++m) {
#pragma unroll
    for (int r = 0; r < 4; ++r) {
      int row = row0 + m * 16 + fq * 4 + r;
      float xm = Amax[row];
      float* orow = out + (size_t)row * N;
#pragma unroll
      for (int n = 0; n < 4; ++n) {
        float v = (float)acc[m][n][r] * C;
        float h = __half2float(__float2half_rn(v));  // fp16 rounding step
        orow[col0 + n * 16 + fr] = h * (xm * wmx[n]) + bs[n];
      }
    }
  }
}

extern "C" void kernel_launch(void* const* d_in, const int* in_sizes, int n_in,
                              void* d_out, int out_size, void* d_ws, size_t ws_size,
                              hipStream_t stream) {
  const float* x = (const float*)d_in[0];     // [B,S,K] fp32
  const float* w = (const float*)d_in[1];     // [N,K] fp32
  const float* bias = (const float*)d_in[2];  // [N] fp32
  float* out = (float*)d_out;                 // [B,S,N] fp32

  const int N = in_sizes[2];
  const int K = in_sizes[1] / N;   // 1024
  const int M = in_sizes[0] / K;   // 32768

  // workspace layout: x_q | w_q | x_max | w_max  (~34.7 MB total)
  signed char* xq = (signed char*)d_ws;
  signed char* wq = xq + (size_t)M * K;
  float* xmax = (float*)(wq + (size_t)N * K);
  float* wmax = xmax + M;

  // Merged quant: one launch, M+N blocks (w rows overlap x rows).
  quant_rows_kernel<<<M + N, 256, 0, stream>>>(x, xq, xmax, w, wq, wmax, K, M,
                                               N);

  const int nwg = (M / BM) * (N / BN);  // 2048, divisible by 8
  const int cpx = nwg / 8;
  w8x8_gemm_kernel<<<nwg, 256, 0, stream>>>(xq, wq, xmax, wmax, bias, out,
                                            M, N, K, cpx);
}

// Round 17
// 86.543 us; speedup vs baseline: 1.0892x; 1.0018x over previous
//
#include <hip/hip_runtime.h>
#include <hip/hip_fp16.h>

// W8X8Linear: per-row int8 quant (x and w), int8 GEMM via MFMA, dequant+bias.
// M=B*S=32768, N=1024, K=1024 (derived from in_sizes at launch).
//
// Exact-replication notes:
//  - jnp.round == round-half-even == rintf (v_rndne_f32)
//  - scale 127.0f/max (fp32 div) then fp32 mul, like the reference
//  - int32 accumulation == reference's fp32 einsum (|acc| < 2^24, exact)
//  - dequant: * (1/16129), fp16 RN cast, fp32 * (xmax*wmax) + bias
//
// Ladder: R6 K-BLOCKED quant layout (contiguous staging): 95us. R9 thin regs
//   -> 4 waves/SIMD: 89us. R15 merged quant launch: 86.7us BEST. Nulls:
//   schedule variants x6, A-direct x4, min-wave clamp (spill), 2-buf
//   single-barrier (RACE — end barrier is load-bearing with 2 buffers).
// R16: traffic lever at CONSTANT occupancy: 256x128 tile, 8 waves (4Mx2N,
//   per-wave 64x64 — identical per-wave geometry/protocol to R15). Staged
//   traffic M*N*K*(1/BM+1/BN): 512->384 MB (-25%), stage stmts/CU -25%.
//   3 stmts/K-tile -> steady-state vmcnt(3). 48KB LDS -> 2 blocks/CU
//   (16 waves/CU, same as R15's 4x4). launch_bounds(512,4) = same 128 cap.

typedef int i32x4 __attribute__((ext_vector_type(4)));

#define BM 256
#define BN 128
#define KB 64  // K-bytes per tile = quant layout block size

// ---- quantize: one block per row of x (b<M) or w (b>=M); K-BLOCKED output --
__global__ __launch_bounds__(256) void quant_rows_kernel(
    const float* __restrict__ x, signed char* __restrict__ xq,
    float* __restrict__ xmax, const float* __restrict__ w,
    signed char* __restrict__ wq, float* __restrict__ wmax, int K, int M,
    int N) {
  const int b = blockIdx.x;
  const bool isx = (b < M);
  const int row = isx ? b : b - M;
  const int R = isx ? M : N;
  const float* in = isx ? x : w;
  signed char* q = isx ? xq : wq;
  float* rowmax = isx ? xmax : wmax;

  const int t = threadIdx.x;
  const size_t base = (size_t)row * K;
  float4 v = reinterpret_cast<const float4*>(in + base)[t];
  float a = fmaxf(fmaxf(fabsf(v.x), fabsf(v.y)), fmaxf(fabsf(v.z), fabsf(v.w)));
#pragma unroll
  for (int off = 32; off > 0; off >>= 1) a = fmaxf(a, __shfl_xor(a, off, 64));
  __shared__ float smax[4];
  if ((t & 63) == 0) smax[t >> 6] = a;
  __syncthreads();
  float m = fmaxf(fmaxf(smax[0], smax[1]), fmaxf(smax[2], smax[3]));
  float s = 127.0f / m;  // fp32 divide, same as reference
  char4 qq;
  qq.x = (signed char)(int)rintf(v.x * s);
  qq.y = (signed char)(int)rintf(v.y * s);
  qq.z = (signed char)(int)rintf(v.z * s);
  qq.w = (signed char)(int)rintf(v.w * s);
  // elems k = 4t..4t+3 -> kb = t>>4, within-block byte (t&15)*4
  const int kb = t >> 4;
  signed char* dst = q + (size_t)kb * R * KB + (size_t)row * KB + (t & 15) * 4;
  *reinterpret_cast<char4*>(dst) = qq;
  if (t == 0) rowmax[row] = m;
}

// ---------- int8 GEMM, 256x128 tile, 8 waves (4M x 2N), BK=64 ---------------
__device__ __forceinline__ void gload_lds16(const void* g, void* l) {
  __builtin_amdgcn_global_load_lds(
      (const __attribute__((address_space(1))) unsigned char*)g,
      (__attribute__((address_space(3))) unsigned char*)l, 16, 0, 0);
}

__global__ __launch_bounds__(512, 4) void w8x8_gemm_kernel(
    const signed char* __restrict__ Aq, const signed char* __restrict__ Bq,
    const float* __restrict__ Amax, const float* __restrict__ Bmax,
    const float* __restrict__ bias, float* __restrict__ out,
    int M, int N, int K, int cpx) {
  // 2 buffers x (A 16 KB + B 8 KB) = 48 KB -> 2 blocks/CU (16 waves/CU).
  __shared__ __align__(16) signed char ldsA[2][BM * KB];
  __shared__ __align__(16) signed char ldsB[2][BN * KB];
  const int t = threadIdx.x;
  const int lane = t & 63;
  const int wave = t >> 6;
  const int wrow = wave >> 1;  // 0..3 (M quarter, 64 rows)
  const int wcol = wave & 1;   // 0..1 (N half, 64 cols)

  // XCD-chunked swizzle: 1024 blocks, 128/XCD; per-XCD A slice =
  // 16 bm x 256 rows x 1 KB = 4 MB (one L2).
  const int nbn = N / BN;  // 8
  const int bid = blockIdx.x;
  const int tile = (bid & 7) * cpx + (bid >> 3);
  const int bm = tile / nbn, bn = tile % nbn;

  // K-blocked layout: A tile kt CONTIGUOUS 16 KB, B tile kt CONTIGUOUS 8 KB.
  const size_t kbA = (size_t)M * KB;
  const size_t kbB = (size_t)N * KB;
  const signed char* Abase = Aq + (size_t)bm * BM * KB;
  const signed char* Bbase = Bq + (size_t)bn * BN * KB;

  // Staging (512 thr x 16 B = 8 KB/stmt): A = 2 stmts (rows 0-127, 128-255),
  // B = 1 stmt. Chunk t: row r = t>>2; source pre-swizzled phys chunk
  // (t&3) ^ ((r>>1)&3) = (t&3) ^ ((t>>3)&3). Row offset +128 (stmt 2)
  // preserves (r>>1)&3 (128 = 0 mod 8).
  const int rS = t >> 2;
  const int gs0 = (rS << 6) | ((((t & 3) ^ ((rS >> 1) & 3))) << 4);
  const int dst0 = t * 16;

  // Fragment reads (swizzled): frag row ra, k-chunk fq -> phys chunk
  // fq ^ ((ra>>1)&3); (ra>>1)&3 == (fr>>1)&3 (row bases multiples of 16).
  const int fr = lane & 15, fq = lane >> 4;
  const int pcs = (fq ^ ((fr >> 1) & 3)) << 4;
  int aoff[4], boff[4];
#pragma unroll
  for (int m = 0; m < 4; ++m) {
    aoff[m] = (wrow * 64 + m * 16 + fr) * KB + pcs;
    boff[m] = (wcol * 64 + m * 16 + fr) * KB + pcs;
  }

  i32x4 acc[4][4];
#pragma unroll
  for (int m = 0; m < 4; ++m)
#pragma unroll
    for (int n = 0; n < 4; ++n) acc[m][n] = (i32x4){0, 0, 0, 0};

#define STAGE(bf, kt)                                                  \
  do {                                                                 \
    const signed char* ga = Abase + (size_t)(kt) * kbA + gs0;          \
    const signed char* gb = Bbase + (size_t)(kt) * kbB + gs0;          \
    gload_lds16(ga, &ldsA[bf][dst0]);                                  \
    gload_lds16(ga + 8192, &ldsA[bf][dst0 + 8192]);                    \
    gload_lds16(gb, &ldsB[bf][dst0]);                                  \
  } while (0)

  const int NT = K / KB;  // 16
  STAGE(0, 0);

  for (int kt = 0; kt < NT; ++kt) {
    const bool pf = (kt + 1 < NT);
    // 1) issue next tile's staging (other buffer; readers passed the END
    //    barrier of iter kt-1 — load-bearing with 2 buffers, see R14).
    if (pf) STAGE((kt + 1) & 1, kt + 1);
    // 2) counted wait: tile kt's 3 loads (issued LAST iter = full iteration
    //    of cover) retired; kt+1's 3 stay in flight ACROSS the barrier.
    if (pf)
      asm volatile("s_waitcnt vmcnt(3)" ::: "memory");
    else
      asm volatile("s_waitcnt vmcnt(0)" ::: "memory");
    __builtin_amdgcn_s_barrier();  // all waves' tile-kt loads landed

    // 3) compute tile kt
    const signed char* lA = ldsA[kt & 1];
    const signed char* lB = ldsB[kt & 1];
    i32x4 a[4], b[4];
#pragma unroll
    for (int m = 0; m < 4; ++m) {
      a[m] = *reinterpret_cast<const i32x4*>(lA + aoff[m]);
      b[m] = *reinterpret_cast<const i32x4*>(lB + boff[m]);
    }
    __builtin_amdgcn_s_setprio(1);
#pragma unroll
    for (int m = 0; m < 4; ++m)
#pragma unroll
      for (int n = 0; n < 4; ++n)
        acc[m][n] = __builtin_amdgcn_mfma_i32_16x16x64_i8(a[m], b[n],
                                                          acc[m][n], 0, 0, 0);
    __builtin_amdgcn_s_setprio(0);

    // 4) END barrier: protects buf (kt+1)&1 from iter kt+1's staging while
    //    lagging waves still read it. REQUIRED with 2 buffers (R14 raced).
    if (pf) __builtin_amdgcn_s_barrier();
  }
#undef STAGE

  // Epilogue: C/D layout col = lane&15, row = (lane>>4)*4 + reg.
  // Per store instr: 4 segments x 64 B (good coalescing).
  const int row0 = bm * BM + wrow * 64;
  const int col0 = bn * BN + wcol * 64;
  const float C = 1.0f / 16129.0f;
  float wmx[4], bs[4];
#pragma unroll
  for (int n = 0; n < 4; ++n) {
    int col = col0 + n * 16 + fr;
    wmx[n] = Bmax[col];
    bs[n] = bias[col];
  }
#pragma unroll
  for (int m = 0; m < 4; ++m) {
#pragma unroll
    for (int r = 0; r < 4; ++r) {
      int row = row0 + m * 16 + fq * 4 + r;
      float xm = Amax[row];
      float* orow = out + (size_t)row * N;
#pragma unroll
      for (int n = 0; n < 4; ++n) {
        float v = (float)acc[m][n][r] * C;
        float h = __half2float(__float2half_rn(v));  // fp16 rounding step
        orow[col0 + n * 16 + fr] = h * (xm * wmx[n]) + bs[n];
      }
    }
  }
}

extern "C" void kernel_launch(void* const* d_in, const int* in_sizes, int n_in,
                              void* d_out, int out_size, void* d_ws, size_t ws_size,
                              hipStream_t stream) {
  const float* x = (const float*)d_in[0];     // [B,S,K] fp32
  const float* w = (const float*)d_in[1];     // [N,K] fp32
  const float* bias = (const float*)d_in[2];  // [N] fp32
  float* out = (float*)d_out;                 // [B,S,N] fp32

  const int N = in_sizes[2];
  const int K = in_sizes[1] / N;   // 1024
  const int M = in_sizes[0] / K;   // 32768

  // workspace layout: x_q | w_q | x_max | w_max  (~34.7 MB total)
  signed char* xq = (signed char*)d_ws;
  signed char* wq = xq + (size_t)M * K;
  float* xmax = (float*)(wq + (size_t)N * K);
  float* wmax = xmax + M;

  // Merged quant: one launch, M+N blocks (w rows overlap x rows).
  quant_rows_kernel<<<M + N, 256, 0, stream>>>(x, xq, xmax, w, wq, wmax, K, M,
                                               N);

  const int nwg = (M / BM) * (N / BN);  // 1024, divisible by 8
  const int cpx = nwg / 8;
  w8x8_gemm_kernel<<<nwg, 512, 0, stream>>>(xq, wq, xmax, wmax, bias, out,
                                            M, N, K, cpx);
}